// Round 1
// baseline (194.139 us; speedup 1.0000x reference)
//
#include <hip/hip_runtime.h>
#include <hip/hip_bf16.h>
#include <math.h>
#include <stdint.h>

#define B 4
#define S 2048
#define D 512
#define H 8
#define HD 64

typedef __attribute__((ext_vector_type(4))) int   int4v;
typedef __attribute__((ext_vector_type(8))) short short8;
typedef __attribute__((ext_vector_type(4))) short short4v;
typedef __attribute__((ext_vector_type(4))) float f32x4;

__device__ __forceinline__ unsigned short bfr(float x) {
    __bf16 h = (__bf16)x;
    union { __bf16 b; unsigned short s; } u; u.b = h; return u.s;
}
__device__ __forceinline__ float b2f(unsigned short s) {
    union { unsigned u; float f; } v; v.u = (unsigned)s << 16; return v.f;
}
__device__ __forceinline__ float ex2(float x) {
#if __has_builtin(__builtin_amdgcn_exp2f)
    return __builtin_amdgcn_exp2f(x);
#else
    return exp2f(x);
#endif
}
__device__ __forceinline__ short8 cvt8(const float* p) {
    float4 f0 = *(const float4*)p;
    float4 f1 = *(const float4*)(p + 4);
    short8 s8;
    s8[0] = (short)bfr(f0.x); s8[1] = (short)bfr(f0.y);
    s8[2] = (short)bfr(f0.z); s8[3] = (short)bfr(f0.w);
    s8[4] = (short)bfr(f1.x); s8[5] = (short)bfr(f1.y);
    s8[6] = (short)bfr(f1.z); s8[7] = (short)bfr(f1.w);
    return s8;
}

// log2e / sqrt(512): folded into Qh at projection time
#define QSCALE 0.06377229601488305f
// fixed log2-domain softmax max (scores |z| <~ 1; exact for any M). With
// k-split this makes partial (acc, l) sums EXACTLY mergeable by addition.
#define MFIX 4.0f

typedef const __attribute__((address_space(1))) unsigned char g8_t;
typedef __attribute__((address_space(3))) unsigned char l8_t;
__device__ __forceinline__ void gl_lds16(const unsigned short* g, unsigned short* l) {
#if __has_builtin(__builtin_amdgcn_global_load_lds)
    __builtin_amdgcn_global_load_lds((g8_t*)g, (l8_t*)l, 16, 0, 0);
#else
    int lane = threadIdx.x & 63;
    ((int4v*)l)[lane] = *(const int4v*)g;
#endif
}

// ===========================================================================
// Kernel 1: QKV projection (+ distributed Wo fp32->bf16 conversion).
// 1536 work blocks + 256 WoB blocks, 256 thr.
// ===========================================================================
__global__ __launch_bounds__(256) void qkv_mfma_kernel(
    const float* __restrict__ q, const float* __restrict__ k,
    const float* __restrict__ v,
    const float* __restrict__ Wq, const float* __restrict__ bq,
    const float* __restrict__ Wk, const float* __restrict__ bk,
    const float* __restrict__ Wv, const float* __restrict__ bv,
    const float* __restrict__ Wo, unsigned short* __restrict__ WoB,
    unsigned short* __restrict__ Qh, unsigned short* __restrict__ Kh,
    unsigned short* __restrict__ VtG)
{
    const int t = threadIdx.x;
    const int bid = blockIdx.x;
    if (bid >= 1536) {
        int i = (bid - 1536) * 1024 + t * 4;
        float4 f = *(const float4*)(Wo + i);
        short4v s;
        s[0] = (short)bfr(f.x); s[1] = (short)bfr(f.y);
        s[2] = (short)bfr(f.z); s[3] = (short)bfr(f.w);
        *(short4v*)(WoB + i) = s;
        return;
    }

    __shared__ __align__(16) unsigned short Wl[64 * 72];

    const int x   = bid / 512;
    const int r_  = bid - x * 512;
    const int bh  = r_ >> 4;
    const int stg = r_ & 15;
    const int b = bh >> 3, h = bh & 7;
    const int L = t & 63, w = t >> 6;
    const int c = L & 15, qd = L >> 4;

    const float* Wf     = (x == 0) ? Wq : (x == 1) ? Wk : Wv;
    const float* bias_p = (x == 0) ? bq : (x == 1) ? bk : bv;
    const float* X      = (x == 0) ? q  : (x == 1) ? k  : v;

    {
        int row = t >> 2, col = (t & 3) * 16;
        *(short8*)&Wl[row * 72 + col]     = cvt8(Wf + t * 16);
        *(short8*)&Wl[row * 72 + col + 8] = cvt8(Wf + t * 16 + 8);
    }
    __syncthreads();

    short8 wf[4][2];
    #pragma unroll
    for (int nt = 0; nt < 4; ++nt)
        #pragma unroll
        for (int kc = 0; kc < 2; ++kc)
            wf[nt][kc] = *(const short8*)&Wl[(16 * nt + c) * 72 + kc * 32 + 8 * qd];

    if (x < 2) {
        float bias[4];
        #pragma unroll
        for (int nt = 0; nt < 4; ++nt) bias[nt] = bias_p[16 * nt + c];
        const float sc = (x == 0) ? QSCALE : 1.0f;
        #pragma unroll
        for (int ti = 0; ti < 2; ++ti) {
            const int st = stg * 8 + w * 2 + ti;
            const float* xrow = X + ((size_t)(b * S + st * 16 + c)) * D + h * HD;
            short8 af0 = cvt8(xrow + 8 * qd);
            short8 af1 = cvt8(xrow + 32 + 8 * qd);
            f32x4 acc[4];
            #pragma unroll
            for (int nt = 0; nt < 4; ++nt) {
                acc[nt] = (f32x4){bias[nt], bias[nt], bias[nt], bias[nt]};
                acc[nt] = __builtin_amdgcn_mfma_f32_16x16x32_bf16(af0, wf[nt][0], acc[nt], 0, 0, 0);
                acc[nt] = __builtin_amdgcn_mfma_f32_16x16x32_bf16(af1, wf[nt][1], acc[nt], 0, 0, 0);
            }
            unsigned short* O = ((x == 0) ? Qh : Kh)
                              + ((size_t)(b * H + h) * S + st * 16) * HD;
            #pragma unroll
            for (int nt = 0; nt < 4; ++nt)
                #pragma unroll
                for (int r = 0; r < 4; ++r)
                    O[(4 * qd + r) * HD + 16 * nt + c] = bfr(acc[nt][r] * sc);
        }
    } else {
        f32x4 bias4[4];
        #pragma unroll
        for (int nt = 0; nt < 4; ++nt) {
            float4 bb4 = *(const float4*)(bias_p + 16 * nt + 4 * qd);
            bias4[nt] = (f32x4){bb4.x, bb4.y, bb4.z, bb4.w};
        }
        #pragma unroll
        for (int ti = 0; ti < 2; ++ti) {
            const int st = stg * 8 + w * 2 + ti;
            const float* xrow = X + ((size_t)(b * S + st * 16 + c)) * D + h * HD;
            short8 af0 = cvt8(xrow + 8 * qd);
            short8 af1 = cvt8(xrow + 32 + 8 * qd);
            f32x4 acc[4];
            #pragma unroll
            for (int nt = 0; nt < 4; ++nt) {
                acc[nt] = bias4[nt];
                acc[nt] = __builtin_amdgcn_mfma_f32_16x16x32_bf16(wf[nt][0], af0, acc[nt], 0, 0, 0);
                acc[nt] = __builtin_amdgcn_mfma_f32_16x16x32_bf16(wf[nt][1], af1, acc[nt], 0, 0, 0);
            }
            unsigned short* O = VtG + (size_t)(b * H + h) * HD * S;
            #pragma unroll
            for (int nt = 0; nt < 4; ++nt)
                #pragma unroll
                for (int r = 0; r < 4; ++r)
                    O[(size_t)(16 * nt + 4 * qd + r) * S + st * 16 + c] = bfr(acc[nt][r]);
        }
    }
}

// ===========================================================================
// Kernel 2: flash attention, 1024 blocks x 256 thr, 4 blocks/CU, 32 KB LDS.
// k-split 2 with fixed log2-domain max -> partial (acc,l) merge by addition.
// T5: s_setprio(1) tightly around MFMA clusters (4 blocks/CU at independent
// phases -> CU scheduler can prefer the MFMA-issuing wave).
// ===========================================================================
__global__ __launch_bounds__(256, 4) void attn_kernel(
    const unsigned short* __restrict__ Qh, const unsigned short* __restrict__ Kh,
    const unsigned short* __restrict__ VtG, unsigned short* __restrict__ accPb,
    float* __restrict__ lP)
{
    __shared__ __align__(16) unsigned short Ks[2][4096];
    __shared__ __align__(16) unsigned short Vs[2][4096];

    const int idx = blockIdx.x;
    const int bh = idx & 31;
    const int rem = idx >> 5;
    const int qt = rem >> 1;
    const int ks = rem & 1;
    const int b = bh >> 3, h = bh & 7;
    const int t = threadIdx.x;
    const int w = t >> 6, L = t & 63;
    const int c = L & 15, qd = L >> 4;

    const unsigned short* Kb = Kh + ((size_t)bh * S + ks * 1024) * HD;
    const unsigned short* Vb = VtG + (size_t)bh * HD * S + ks * 1024;

    short8 qf[2][2];
    #pragma unroll
    for (int qg = 0; qg < 2; ++qg)
        #pragma unroll
        for (int kc = 0; kc < 2; ++kc)
            qf[qg][kc] = *(const short8*)(Qh
                + ((size_t)bh * S + qt * 128 + w * 32 + qg * 16 + c) * HD
                + kc * 32 + 8 * qd);

    f32x4 acc[2][4];
    float lrun[2] = {0.f, 0.f};
    #pragma unroll
    for (int qg = 0; qg < 2; ++qg)
        #pragma unroll
        for (int dt = 0; dt < 4; ++dt) acc[qg][dt] = (f32x4){0.f, 0.f, 0.f, 0.f};

    const int sd = t >> 3, sj = t & 7;
    const int sp = sj >> 2, smt = (sj >> 1) & 1;
    const int sqa = (2 * sj) & 3, sqb = (2 * sj + 1) & 3;

    int4v vpre[2];
    #pragma unroll
    for (int i = 0; i < 2; ++i) {
        int bi = w + 4 * i;
        gl_lds16(Kb + (size_t)(16 * (bi >> 1) + c) * HD + (bi & 1) * 32 + qd * 8,
                 &Ks[0][bi * 512]);
        vpre[i] = *(const int4v*)(Vb + (size_t)(sd + 32 * i) * S + 8 * sj);
    }

    for (int it = 0; it < 16; ++it) {
        const int cur = it & 1, nxt = cur ^ 1;
        #pragma unroll
        for (int i = 0; i < 2; ++i) {
            int d = sd + 32 * i;
            int dt = d >> 4, cc = d & 15;
            union { int4v v; short4v h[2]; } u; u.v = vpre[i];
            *(short4v*)&Vs[cur][((dt * 2 + sp) * 64 + sqa * 16 + cc) * 8 + smt * 4] = u.h[0];
            *(short4v*)&Vs[cur][((dt * 2 + sp) * 64 + sqb * 16 + cc) * 8 + smt * 4] = u.h[1];
        }
        __syncthreads();
        if (it + 1 < 16) {
            int n1 = (it + 1) * 64;
            #pragma unroll
            for (int i = 0; i < 2; ++i) {
                int bi = w + 4 * i;
                gl_lds16(Kb + (size_t)(n1 + 16 * (bi >> 1) + c) * HD + (bi & 1) * 32 + qd * 8,
                         &Ks[nxt][bi * 512]);
                vpre[i] = *(const int4v*)(Vb + (size_t)(sd + 32 * i) * S + n1 + 8 * sj);
            }
        }

        const unsigned short* KsC = Ks[cur];
        const unsigned short* VsC = Vs[cur];

        short4v pa[2][4];
        #pragma unroll
        for (int mt = 0; mt < 4; ++mt) {
            short8 a0 = *(const short8*)(KsC + (mt * 2 + 0) * 512 + L * 8);
            short8 a1 = *(const short8*)(KsC + (mt * 2 + 1) * 512 + L * 8);
            #pragma unroll
            for (int qg = 0; qg < 2; ++qg) {
                f32x4 stv = (f32x4){-MFIX, -MFIX, -MFIX, -MFIX};
                __builtin_amdgcn_s_setprio(1);
                stv = __builtin_amdgcn_mfma_f32_16x16x32_bf16(a0, qf[qg][0], stv, 0, 0, 0);
                stv = __builtin_amdgcn_mfma_f32_16x16x32_bf16(a1, qf[qg][1], stv, 0, 0, 0);
                __builtin_amdgcn_s_setprio(0);
                float p0 = ex2(stv[0]), p1 = ex2(stv[1]);
                float p2 = ex2(stv[2]), p3 = ex2(stv[3]);
                lrun[qg] += (p0 + p1) + (p2 + p3);
                short4v p_;
                p_[0] = (short)bfr(p0); p_[1] = (short)bfr(p1);
                p_[2] = (short)bfr(p2); p_[3] = (short)bfr(p3);
                pa[qg][mt] = p_;
            }
        }

        #pragma unroll
        for (int dt = 0; dt < 4; ++dt)
            #pragma unroll
            for (int p = 0; p < 2; ++p) {
                union { short8 v8; short4v h[2]; } u;
                u.v8 = *(const short8*)(VsC + (dt * 2 + p) * 512 + L * 8);
#if __has_builtin(__builtin_amdgcn_mfma_f32_16x16x16bf16_1k)
                __builtin_amdgcn_s_setprio(1);
                #pragma unroll
                for (int qg = 0; qg < 2; ++qg) {
                    acc[qg][dt] = __builtin_amdgcn_mfma_f32_16x16x16bf16_1k(
                        pa[qg][2 * p + 0], u.h[0], acc[qg][dt], 0, 0, 0);
                    acc[qg][dt] = __builtin_amdgcn_mfma_f32_16x16x16bf16_1k(
                        pa[qg][2 * p + 1], u.h[1], acc[qg][dt], 0, 0, 0);
                }
                __builtin_amdgcn_s_setprio(0);
#else
                __builtin_amdgcn_s_setprio(1);
                #pragma unroll
                for (int qg = 0; qg < 2; ++qg) {
                    short8 pz0 = {pa[qg][2 * p + 0][0], pa[qg][2 * p + 0][1],
                                  pa[qg][2 * p + 0][2], pa[qg][2 * p + 0][3], 0, 0, 0, 0};
                    short8 pz1 = {pa[qg][2 * p + 1][0], pa[qg][2 * p + 1][1],
                                  pa[qg][2 * p + 1][2], pa[qg][2 * p + 1][3], 0, 0, 0, 0};
                    short8 v0 = {u.h[0][0], u.h[0][1], u.h[0][2], u.h[0][3], 0, 0, 0, 0};
                    short8 v1 = {u.h[1][0], u.h[1][1], u.h[1][2], u.h[1][3], 0, 0, 0, 0};
                    acc[qg][dt] = __builtin_amdgcn_mfma_f32_16x16x32_bf16(pz0, v0, acc[qg][dt], 0, 0, 0);
                    acc[qg][dt] = __builtin_amdgcn_mfma_f32_16x16x32_bf16(pz1, v1, acc[qg][dt], 0, 0, 0);
                }
                __builtin_amdgcn_s_setprio(0);
#endif
            }
    }

    const int q0 = qt * 128 + w * 32;
    unsigned short* accPp = accPb + (size_t)ks * ((size_t)B * S * D)
                          + ((size_t)b * S + q0) * D + h * HD;
    #pragma unroll
    for (int qg = 0; qg < 2; ++qg) {
        float lr = lrun[qg];
        lr += __shfl_xor(lr, 16);
        lr += __shfl_xor(lr, 32);
        if (qd == 0)
            lP[(size_t)ks * ((size_t)B * H * S) + (size_t)bh * S + q0 + qg * 16 + c] = lr;
        #pragma unroll
        for (int dt = 0; dt < 4; ++dt)
            #pragma unroll
            for (int r = 0; r < 4; ++r)
                accPp[(size_t)(qg * 16 + 4 * qd + r) * D + 16 * dt + c]
                    = bfr(acc[qg][dt][r]);
    }
}

// ===========================================================================
// Kernel 3: merge k-split partials + output projection + LayerNorm + residual
// ===========================================================================
__global__ __launch_bounds__(1024) void oproj_ln_kernel(
    const unsigned short* __restrict__ accPb, const float* __restrict__ lP,
    const unsigned short* __restrict__ WoB,
    const float* __restrict__ bo, const float* __restrict__ gamma,
    const float* __restrict__ beta, const float* __restrict__ qin,
    float* __restrict__ out)
{
    __shared__ __align__(16) unsigned short As[32 * 520];
    __shared__ float red[2][32][17];
    __shared__ float linv_s[32][8];
    __shared__ float mu_s2[32], rs_s2[32];

    const int t = threadIdx.x;
    const int r0 = blockIdx.x * 32;
    const int w = t >> 6, L = t & 63;
    const int c = L & 15, qd = L >> 4;
    const int n0 = w * 32;
    const size_t NEh = (size_t)B * S * D;
    const size_t BHS = (size_t)B * H * S;

    if (t < 256) {
        int row = t >> 3, hh = t & 7;
        int bb = r0 >> 11;
        int ss = (r0 & (S - 1)) + row;
        float l0 = lP[(size_t)(bb * H + hh) * S + ss];
        float l1 = lP[BHS + (size_t)(bb * H + hh) * S + ss];
        linv_s[row][hh] = 1.f / (l0 + l1);
    }
    __syncthreads();

    #pragma unroll
    for (int i = 0; i < 4; ++i) {
        int flat = t + 1024 * i;
        int row = flat >> 7, cg4 = flat & 127;
        int col = cg4 * 4;
        size_t gi = (size_t)(r0 + row) * D + col;
        short4v a0 = *(const short4v*)(accPb + gi);
        short4v a1 = *(const short4v*)(accPb + NEh + gi);
        float li = linv_s[row][col >> 6];
        short4v s;
        #pragma unroll
        for (int j = 0; j < 4; ++j)
            s[j] = (short)bfr((b2f((unsigned short)a0[j])
                             + b2f((unsigned short)a1[j])) * li);
        *(short4v*)&As[row * 520 + col] = s;
    }
    __syncthreads();

    f32x4 acc[2][2];
    #pragma unroll
    for (int nt = 0; nt < 2; ++nt) {
        float bv_ = bo[n0 + 16 * nt + c];
        acc[0][nt] = (f32x4){bv_, bv_, bv_, bv_};
        acc[1][nt] = (f32x4){bv_, bv_, bv_, bv_};
    }

    for (int kc = 0; kc < 16; ++kc) {
        short8 a0 = *(const short8*)&As[c * 520 + kc * 32 + 8 * qd];
        short8 a1 = *(const short8*)&As[(16 + c) * 520 + kc * 32 + 8 * qd];
        #pragma unroll
        for (int nt = 0; nt < 2; ++nt) {
            short8 bf = *(const short8*)(WoB + (size_t)(n0 + 16 * nt + c) * D
                                         + kc * 32 + 8 * qd);
            acc[0][nt] = __builtin_amdgcn_mfma_f32_16x16x32_bf16(a0, bf, acc[0][nt], 0, 0, 0);
            acc[1][nt] = __builtin_amdgcn_mfma_f32_16x16x32_bf16(a1, bf, acc[1][nt], 0, 0, 0);
        }
    }

    float sm[2][4], sq[2][4];
    #pragma unroll
    for (int mt = 0; mt < 2; ++mt)
        #pragma unroll
        for (int r = 0; r < 4; ++r) { sm[mt][r] = 0.f; sq[mt][r] = 0.f; }
    #pragma unroll
    for (int mt = 0; mt < 2; ++mt)
        #pragma unroll
        for (int nt = 0; nt < 2; ++nt)
            #pragma unroll
            for (int r = 0; r < 4; ++r) {
                float x_ = acc[mt][nt][r];
                sm[mt][r] += x_; sq[mt][r] += x_ * x_;
            }
    #pragma unroll
    for (int mask = 1; mask <= 8; mask <<= 1)
        #pragma unroll
        for (int mt = 0; mt < 2; ++mt)
            #pragma unroll
            for (int r = 0; r < 4; ++r) {
                sm[mt][r] += __shfl_xor(sm[mt][r], mask);
                sq[mt][r] += __shfl_xor(sq[mt][r], mask);
            }
    if (c == 0) {
        #pragma unroll
        for (int mt = 0; mt < 2; ++mt)
            #pragma unroll
            for (int r = 0; r < 4; ++r) {
                red[0][mt * 16 + 4 * qd + r][w] = sm[mt][r];
                red[1][mt * 16 + 4 * qd + r][w] = sq[mt][r];
            }
    }
    __syncthreads();

    if (t < 32) {
        float s_ = 0.f, q_ = 0.f;
        #pragma unroll
        for (int w_ = 0; w_ < 16; ++w_) { s_ += red[0][t][w_]; q_ += red[1][t][w_]; }
        float mu_ = s_ * (1.f / D);
        float var = q_ * (1.f / D) - mu_ * mu_;
        mu_s2[t] = mu_;
        rs_s2[t] = rsqrtf(var + 1e-5f);
    }
    __syncthreads();

    #pragma unroll
    for (int nt = 0; nt < 2; ++nt) {
        int n = n0 + 16 * nt + c;
        float g = gamma[n], be = beta[n];
        #pragma unroll
        for (int mt = 0; mt < 2; ++mt)
            #pragma unroll
            for (int r = 0; r < 4; ++r) {
                int m = mt * 16 + 4 * qd + r;
                size_t gi = (size_t)(r0 + m) * D + n;
                out[gi] = qin[gi] + (acc[mt][nt][r] - mu_s2[m]) * rs_s2[m] * g + be;
            }
    }
}

// ---------------------------------------------------------------------------
extern "C" void kernel_launch(void* const* d_in, const int* in_sizes, int n_in,
                              void* d_out, int out_size, void* d_ws, size_t ws_size,
                              hipStream_t stream) {
    const float* q     = (const float*)d_in[0];
    const float* k     = (const float*)d_in[1];
    const float* v     = (const float*)d_in[2];
    const float* Wq    = (const float*)d_in[3];
    const float* bq    = (const float*)d_in[4];
    const float* Wk    = (const float*)d_in[5];
    const float* bk    = (const float*)d_in[6];
    const float* Wv    = (const float*)d_in[7];
    const float* bv    = (const float*)d_in[8];
    const float* Wo    = (const float*)d_in[9];
    const float* bo    = (const float*)d_in[10];
    const float* gamma = (const float*)d_in[11];
    const float* beta  = (const float*)d_in[12];
    float* out = (float*)d_out;

    const size_t NE = (size_t)B * S * D;
    unsigned short* wsu = (unsigned short*)d_ws;
    unsigned short* Qh    = wsu;
    unsigned short* Kh    = wsu + NE;
    unsigned short* VtG   = wsu + 2 * NE;
    unsigned short* WoB   = wsu + 3 * NE;
    unsigned short* accPb = WoB + (size_t)D * D;
    float* lP = (float*)(accPb + 2 * NE);

    hipLaunchKernelGGL(qkv_mfma_kernel, dim3(1536 + 256), dim3(256), 0, stream,
                       q, k, v, Wq, bq, Wk, bk, Wv, bv, Wo, WoB, Qh, Kh, VtG);
    hipLaunchKernelGGL(attn_kernel, dim3(1024), dim3(256), 0, stream,
                       Qh, Kh, VtG, accPb, lP);
    hipLaunchKernelGGL(oproj_ln_kernel, dim3(B * S / 32), dim3(1024), 0, stream,
                       accPb, lP, WoB, bo, gamma, beta, q, out);
}

// Round 2
// 192.679 us; speedup vs baseline: 1.0076x; 1.0076x over previous
//
#include <hip/hip_runtime.h>
#include <hip/hip_bf16.h>
#include <math.h>
#include <stdint.h>

#define B 4
#define S 2048
#define D 512
#define H 8
#define HD 64

typedef __attribute__((ext_vector_type(4))) int   int4v;
typedef __attribute__((ext_vector_type(8))) short short8;
typedef __attribute__((ext_vector_type(4))) short short4v;
typedef __attribute__((ext_vector_type(4))) float f32x4;

__device__ __forceinline__ unsigned short bfr(float x) {
    __bf16 h = (__bf16)x;
    union { __bf16 b; unsigned short s; } u; u.b = h; return u.s;
}
__device__ __forceinline__ float b2f(unsigned short s) {
    union { unsigned u; float f; } v; v.u = (unsigned)s << 16; return v.f;
}
__device__ __forceinline__ float ex2(float x) {
#if __has_builtin(__builtin_amdgcn_exp2f)
    return __builtin_amdgcn_exp2f(x);
#else
    return exp2f(x);
#endif
}
__device__ __forceinline__ short8 cvt8(const float* p) {
    float4 f0 = *(const float4*)p;
    float4 f1 = *(const float4*)(p + 4);
    short8 s8;
    s8[0] = (short)bfr(f0.x); s8[1] = (short)bfr(f0.y);
    s8[2] = (short)bfr(f0.z); s8[3] = (short)bfr(f0.w);
    s8[4] = (short)bfr(f1.x); s8[5] = (short)bfr(f1.y);
    s8[6] = (short)bfr(f1.z); s8[7] = (short)bfr(f1.w);
    return s8;
}

// log2e / sqrt(512): folded into Qh at projection time
#define QSCALE 0.06377229601488305f
// fixed log2-domain softmax max (scores |z| <~ 1; exact for any M). With
// k-split this makes partial (acc, l) sums EXACTLY mergeable by addition.
#define MFIX 4.0f

typedef const __attribute__((address_space(1))) unsigned char g8_t;
typedef __attribute__((address_space(3))) unsigned char l8_t;
__device__ __forceinline__ void gl_lds16(const unsigned short* g, unsigned short* l) {
#if __has_builtin(__builtin_amdgcn_global_load_lds)
    __builtin_amdgcn_global_load_lds((g8_t*)g, (l8_t*)l, 16, 0, 0);
#else
    int lane = threadIdx.x & 63;
    ((int4v*)l)[lane] = *(const int4v*)g;
#endif
}

// ===========================================================================
// Kernel 1: QKV projection (+ distributed Wo fp32->bf16 conversion).
// 1536 work blocks + 256 WoB blocks, 256 thr.
// Stores routed through a per-wave LDS transpose tile -> 16B coalesced
// global stores (was 32x 2B scattered stores per thread-tile).
// ===========================================================================
__global__ __launch_bounds__(256) void qkv_mfma_kernel(
    const float* __restrict__ q, const float* __restrict__ k,
    const float* __restrict__ v,
    const float* __restrict__ Wq, const float* __restrict__ bq,
    const float* __restrict__ Wk, const float* __restrict__ bk,
    const float* __restrict__ Wv, const float* __restrict__ bv,
    const float* __restrict__ Wo, unsigned short* __restrict__ WoB,
    unsigned short* __restrict__ Qh, unsigned short* __restrict__ Kh,
    unsigned short* __restrict__ VtG)
{
    const int t = threadIdx.x;
    const int bid = blockIdx.x;
    if (bid >= 1536) {
        int i = (bid - 1536) * 1024 + t * 4;
        float4 f = *(const float4*)(Wo + i);
        short4v s;
        s[0] = (short)bfr(f.x); s[1] = (short)bfr(f.y);
        s[2] = (short)bfr(f.z); s[3] = (short)bfr(f.w);
        *(short4v*)(WoB + i) = s;
        return;
    }

    __shared__ __align__(16) unsigned short Wl[64 * 72];
    __shared__ __align__(16) unsigned short Tb[4][1536];   // per-wave transpose tile

    const int x   = bid / 512;
    const int r_  = bid - x * 512;
    const int bh  = r_ >> 4;
    const int stg = r_ & 15;
    const int b = bh >> 3, h = bh & 7;
    const int L = t & 63, w = t >> 6;
    const int c = L & 15, qd = L >> 4;

    const float* Wf     = (x == 0) ? Wq : (x == 1) ? Wk : Wv;
    const float* bias_p = (x == 0) ? bq : (x == 1) ? bk : bv;
    const float* X      = (x == 0) ? q  : (x == 1) ? k  : v;

    unsigned short* Tw = Tb[w];

    {
        int row = t >> 2, col = (t & 3) * 16;
        *(short8*)&Wl[row * 72 + col]     = cvt8(Wf + t * 16);
        *(short8*)&Wl[row * 72 + col + 8] = cvt8(Wf + t * 16 + 8);
    }
    __syncthreads();

    short8 wf[4][2];
    #pragma unroll
    for (int nt = 0; nt < 4; ++nt)
        #pragma unroll
        for (int kc = 0; kc < 2; ++kc)
            wf[nt][kc] = *(const short8*)&Wl[(16 * nt + c) * 72 + kc * 32 + 8 * qd];

    if (x < 2) {
        float bias[4];
        #pragma unroll
        for (int nt = 0; nt < 4; ++nt) bias[nt] = bias_p[16 * nt + c];
        const float sc = (x == 0) ? QSCALE : 1.0f;
        #pragma unroll
        for (int ti = 0; ti < 2; ++ti) {
            const int st = stg * 8 + w * 2 + ti;
            const float* xrow = X + ((size_t)(b * S + st * 16 + c)) * D + h * HD;
            short8 af0 = cvt8(xrow + 8 * qd);
            short8 af1 = cvt8(xrow + 32 + 8 * qd);
            f32x4 acc[4];
            #pragma unroll
            for (int nt = 0; nt < 4; ++nt) {
                acc[nt] = (f32x4){bias[nt], bias[nt], bias[nt], bias[nt]};
                acc[nt] = __builtin_amdgcn_mfma_f32_16x16x32_bf16(af0, wf[nt][0], acc[nt], 0, 0, 0);
                acc[nt] = __builtin_amdgcn_mfma_f32_16x16x32_bf16(af1, wf[nt][1], acc[nt], 0, 0, 0);
            }
            // stage 16(s) x 64(d) tile in LDS (stride 72 keeps 16B-aligned rows)
            #pragma unroll
            for (int nt = 0; nt < 4; ++nt)
                #pragma unroll
                for (int r = 0; r < 4; ++r)
                    Tw[(4 * qd + r) * 72 + 16 * nt + c] = bfr(acc[nt][r] * sc);
            // read back + 16B coalesced stores (rows of 128B)
            int rw = L >> 2, cg_ = (L & 3) * 16;
            short8 s0 = *(const short8*)&Tw[rw * 72 + cg_];
            short8 s1 = *(const short8*)&Tw[rw * 72 + cg_ + 8];
            unsigned short* O = ((x == 0) ? Qh : Kh)
                              + ((size_t)(b * H + h) * S + st * 16) * HD;
            *(short8*)&O[rw * HD + cg_]     = s0;
            *(short8*)&O[rw * HD + cg_ + 8] = s1;
        }
    } else {
        f32x4 bias4[4];
        #pragma unroll
        for (int nt = 0; nt < 4; ++nt) {
            float4 bb4 = *(const float4*)(bias_p + 16 * nt + 4 * qd);
            bias4[nt] = (f32x4){bb4.x, bb4.y, bb4.z, bb4.w};
        }
        #pragma unroll
        for (int ti = 0; ti < 2; ++ti) {
            const int st = stg * 8 + w * 2 + ti;
            const float* xrow = X + ((size_t)(b * S + st * 16 + c)) * D + h * HD;
            short8 af0 = cvt8(xrow + 8 * qd);
            short8 af1 = cvt8(xrow + 32 + 8 * qd);
            f32x4 acc[4];
            #pragma unroll
            for (int nt = 0; nt < 4; ++nt) {
                acc[nt] = bias4[nt];
                acc[nt] = __builtin_amdgcn_mfma_f32_16x16x32_bf16(wf[nt][0], af0, acc[nt], 0, 0, 0);
                acc[nt] = __builtin_amdgcn_mfma_f32_16x16x32_bf16(wf[nt][1], af1, acc[nt], 0, 0, 0);
            }
            // stage 64(d) x 16(s) tile in LDS (stride 24 keeps 16B-aligned rows)
            #pragma unroll
            for (int nt = 0; nt < 4; ++nt)
                #pragma unroll
                for (int r = 0; r < 4; ++r)
                    Tw[(16 * nt + 4 * qd + r) * 24 + c] = bfr(acc[nt][r]);
            // read back: one 32B d-row per lane -> 2x16B stores
            short8 s0 = *(const short8*)&Tw[L * 24];
            short8 s1 = *(const short8*)&Tw[L * 24 + 8];
            unsigned short* O = VtG + (size_t)(b * H + h) * HD * S;
            *(short8*)&O[(size_t)L * S + st * 16]     = s0;
            *(short8*)&O[(size_t)L * S + st * 16 + 8] = s1;
        }
    }
}

// ===========================================================================
// Kernel 2: flash attention, 1024 blocks x 256 thr, 4 blocks/CU, 32 KB LDS.
// k-split 2 with fixed log2-domain max -> partial (acc,l) merge by addition.
// Vs staging uses XOR involution o ^= ((o>>8)&3)<<5 on BOTH write and read
// byte offsets: folds sq bits into bank bits -> 4-way write conflict -> 2-way
// (free). Read side pattern (L*16 sequential) unchanged-conflict-free.
// ===========================================================================
__global__ __launch_bounds__(256, 4) void attn_kernel(
    const unsigned short* __restrict__ Qh, const unsigned short* __restrict__ Kh,
    const unsigned short* __restrict__ VtG, unsigned short* __restrict__ accPb,
    float* __restrict__ lP)
{
    __shared__ __align__(16) unsigned short Ks[2][4096];
    __shared__ __align__(16) unsigned short Vs[2][4096];

    const int idx = blockIdx.x;
    const int bh = idx & 31;
    const int rem = idx >> 5;
    const int qt = rem >> 1;
    const int ks = rem & 1;
    const int b = bh >> 3, h = bh & 7;
    const int t = threadIdx.x;
    const int w = t >> 6, L = t & 63;
    const int c = L & 15, qd = L >> 4;

    const unsigned short* Kb = Kh + ((size_t)bh * S + ks * 1024) * HD;
    const unsigned short* Vb = VtG + (size_t)bh * HD * S + ks * 1024;

    short8 qf[2][2];
    #pragma unroll
    for (int qg = 0; qg < 2; ++qg)
        #pragma unroll
        for (int kc = 0; kc < 2; ++kc)
            qf[qg][kc] = *(const short8*)(Qh
                + ((size_t)bh * S + qt * 128 + w * 32 + qg * 16 + c) * HD
                + kc * 32 + 8 * qd);

    f32x4 acc[2][4];
    float lrun[2] = {0.f, 0.f};
    #pragma unroll
    for (int qg = 0; qg < 2; ++qg)
        #pragma unroll
        for (int dt = 0; dt < 4; ++dt) acc[qg][dt] = (f32x4){0.f, 0.f, 0.f, 0.f};

    const int sd = t >> 3, sj = t & 7;
    const int sp = sj >> 2, smt = (sj >> 1) & 1;
    const int sqa = (2 * sj) & 3, sqb = (2 * sj + 1) & 3;
    // precomputed swizzled Vs byte offsets for the two 8B staging writes
    int voff0 = (((0 * 2 + sp) * 64 + sqa * 16 + 0) * 8 + smt * 4) * 2;
    int voff1 = (((0 * 2 + sp) * 64 + sqb * 16 + 0) * 8 + smt * 4) * 2;

    int4v vpre[2];
    #pragma unroll
    for (int i = 0; i < 2; ++i) {
        int bi = w + 4 * i;
        gl_lds16(Kb + (size_t)(16 * (bi >> 1) + c) * HD + (bi & 1) * 32 + qd * 8,
                 &Ks[0][bi * 512]);
        vpre[i] = *(const int4v*)(Vb + (size_t)(sd + 32 * i) * S + 8 * sj);
    }

    for (int it = 0; it < 16; ++it) {
        const int cur = it & 1, nxt = cur ^ 1;
        unsigned char* VsB = (unsigned char*)&Vs[cur][0];
        #pragma unroll
        for (int i = 0; i < 2; ++i) {
            int d = sd + 32 * i;
            int dt = d >> 4, cc = d & 15;
            union { int4v v; short4v h[2]; } u; u.v = vpre[i];
            int o0 = voff0 + dt * 2048 + cc * 16;
            int o1 = voff1 + dt * 2048 + cc * 16;
            o0 ^= ((o0 >> 8) & 3) << 5;
            o1 ^= ((o1 >> 8) & 3) << 5;
            *(short4v*)(VsB + o0) = u.h[0];
            *(short4v*)(VsB + o1) = u.h[1];
        }
        __syncthreads();
        if (it + 1 < 16) {
            int n1 = (it + 1) * 64;
            #pragma unroll
            for (int i = 0; i < 2; ++i) {
                int bi = w + 4 * i;
                gl_lds16(Kb + (size_t)(n1 + 16 * (bi >> 1) + c) * HD + (bi & 1) * 32 + qd * 8,
                         &Ks[nxt][bi * 512]);
                vpre[i] = *(const int4v*)(Vb + (size_t)(sd + 32 * i) * S + n1 + 8 * sj);
            }
        }

        const unsigned short* KsC = Ks[cur];
        const unsigned char* VsR = (const unsigned char*)&Vs[cur][0];

        short4v pa[2][4];
        #pragma unroll
        for (int mt = 0; mt < 4; ++mt) {
            short8 a0 = *(const short8*)(KsC + (mt * 2 + 0) * 512 + L * 8);
            short8 a1 = *(const short8*)(KsC + (mt * 2 + 1) * 512 + L * 8);
            #pragma unroll
            for (int qg = 0; qg < 2; ++qg) {
                f32x4 stv = (f32x4){-MFIX, -MFIX, -MFIX, -MFIX};
                __builtin_amdgcn_s_setprio(1);
                stv = __builtin_amdgcn_mfma_f32_16x16x32_bf16(a0, qf[qg][0], stv, 0, 0, 0);
                stv = __builtin_amdgcn_mfma_f32_16x16x32_bf16(a1, qf[qg][1], stv, 0, 0, 0);
                __builtin_amdgcn_s_setprio(0);
                float p0 = ex2(stv[0]), p1 = ex2(stv[1]);
                float p2 = ex2(stv[2]), p3 = ex2(stv[3]);
                lrun[qg] += (p0 + p1) + (p2 + p3);
                short4v p_;
                p_[0] = (short)bfr(p0); p_[1] = (short)bfr(p1);
                p_[2] = (short)bfr(p2); p_[3] = (short)bfr(p3);
                pa[qg][mt] = p_;
            }
        }

        #pragma unroll
        for (int dt = 0; dt < 4; ++dt)
            #pragma unroll
            for (int p = 0; p < 2; ++p) {
                int roff = ((dt * 2 + p) * 512 + L * 8) * 2;
                roff ^= ((roff >> 8) & 3) << 5;
                union { short8 v8; short4v h[2]; } u;
                u.v8 = *(const short8*)(VsR + roff);
#if __has_builtin(__builtin_amdgcn_mfma_f32_16x16x16bf16_1k)
                __builtin_amdgcn_s_setprio(1);
                #pragma unroll
                for (int qg = 0; qg < 2; ++qg) {
                    acc[qg][dt] = __builtin_amdgcn_mfma_f32_16x16x16bf16_1k(
                        pa[qg][2 * p + 0], u.h[0], acc[qg][dt], 0, 0, 0);
                    acc[qg][dt] = __builtin_amdgcn_mfma_f32_16x16x16bf16_1k(
                        pa[qg][2 * p + 1], u.h[1], acc[qg][dt], 0, 0, 0);
                }
                __builtin_amdgcn_s_setprio(0);
#else
                __builtin_amdgcn_s_setprio(1);
                #pragma unroll
                for (int qg = 0; qg < 2; ++qg) {
                    short8 pz0 = {pa[qg][2 * p + 0][0], pa[qg][2 * p + 0][1],
                                  pa[qg][2 * p + 0][2], pa[qg][2 * p + 0][3], 0, 0, 0, 0};
                    short8 pz1 = {pa[qg][2 * p + 1][0], pa[qg][2 * p + 1][1],
                                  pa[qg][2 * p + 1][2], pa[qg][2 * p + 1][3], 0, 0, 0, 0};
                    short8 v0 = {u.h[0][0], u.h[0][1], u.h[0][2], u.h[0][3], 0, 0, 0, 0};
                    short8 v1 = {u.h[1][0], u.h[1][1], u.h[1][2], u.h[1][3], 0, 0, 0, 0};
                    acc[qg][dt] = __builtin_amdgcn_mfma_f32_16x16x32_bf16(pz0, v0, acc[qg][dt], 0, 0, 0);
                    acc[qg][dt] = __builtin_amdgcn_mfma_f32_16x16x32_bf16(pz1, v1, acc[qg][dt], 0, 0, 0);
                }
                __builtin_amdgcn_s_setprio(0);
#endif
            }
    }

    const int q0 = qt * 128 + w * 32;
    unsigned short* accPp = accPb + (size_t)ks * ((size_t)B * S * D)
                          + ((size_t)b * S + q0) * D + h * HD;
    #pragma unroll
    for (int qg = 0; qg < 2; ++qg) {
        float lr = lrun[qg];
        lr += __shfl_xor(lr, 16);
        lr += __shfl_xor(lr, 32);
        if (qd == 0)
            lP[(size_t)ks * ((size_t)B * H * S) + (size_t)bh * S + q0 + qg * 16 + c] = lr;
        #pragma unroll
        for (int dt = 0; dt < 4; ++dt)
            #pragma unroll
            for (int r = 0; r < 4; ++r)
                accPp[(size_t)(qg * 16 + 4 * qd + r) * D + 16 * dt + c]
                    = bfr(acc[qg][dt][r]);
    }
}

// ===========================================================================
// Kernel 3: merge k-split partials + output projection + LayerNorm + residual
// ===========================================================================
__global__ __launch_bounds__(1024) void oproj_ln_kernel(
    const unsigned short* __restrict__ accPb, const float* __restrict__ lP,
    const unsigned short* __restrict__ WoB,
    const float* __restrict__ bo, const float* __restrict__ gamma,
    const float* __restrict__ beta, const float* __restrict__ qin,
    float* __restrict__ out)
{
    __shared__ __align__(16) unsigned short As[32 * 520];
    __shared__ float red[2][32][17];
    __shared__ float linv_s[32][8];
    __shared__ float mu_s2[32], rs_s2[32];

    const int t = threadIdx.x;
    const int r0 = blockIdx.x * 32;
    const int w = t >> 6, L = t & 63;
    const int c = L & 15, qd = L >> 4;
    const int n0 = w * 32;
    const size_t NEh = (size_t)B * S * D;
    const size_t BHS = (size_t)B * H * S;

    if (t < 256) {
        int row = t >> 3, hh = t & 7;
        int bb = r0 >> 11;
        int ss = (r0 & (S - 1)) + row;
        float l0 = lP[(size_t)(bb * H + hh) * S + ss];
        float l1 = lP[BHS + (size_t)(bb * H + hh) * S + ss];
        linv_s[row][hh] = 1.f / (l0 + l1);
    }
    __syncthreads();

    #pragma unroll
    for (int i = 0; i < 4; ++i) {
        int flat = t + 1024 * i;
        int row = flat >> 7, cg4 = flat & 127;
        int col = cg4 * 4;
        size_t gi = (size_t)(r0 + row) * D + col;
        short4v a0 = *(const short4v*)(accPb + gi);
        short4v a1 = *(const short4v*)(accPb + NEh + gi);
        float li = linv_s[row][col >> 6];
        short4v s;
        #pragma unroll
        for (int j = 0; j < 4; ++j)
            s[j] = (short)bfr((b2f((unsigned short)a0[j])
                             + b2f((unsigned short)a1[j])) * li);
        *(short4v*)&As[row * 520 + col] = s;
    }
    __syncthreads();

    f32x4 acc[2][2];
    #pragma unroll
    for (int nt = 0; nt < 2; ++nt) {
        float bv_ = bo[n0 + 16 * nt + c];
        acc[0][nt] = (f32x4){bv_, bv_, bv_, bv_};
        acc[1][nt] = (f32x4){bv_, bv_, bv_, bv_};
    }

    for (int kc = 0; kc < 16; ++kc) {
        short8 a0 = *(const short8*)&As[c * 520 + kc * 32 + 8 * qd];
        short8 a1 = *(const short8*)&As[(16 + c) * 520 + kc * 32 + 8 * qd];
        #pragma unroll
        for (int nt = 0; nt < 2; ++nt) {
            short8 bf = *(const short8*)(WoB + (size_t)(n0 + 16 * nt + c) * D
                                         + kc * 32 + 8 * qd);
            acc[0][nt] = __builtin_amdgcn_mfma_f32_16x16x32_bf16(a0, bf, acc[0][nt], 0, 0, 0);
            acc[1][nt] = __builtin_amdgcn_mfma_f32_16x16x32_bf16(a1, bf, acc[1][nt], 0, 0, 0);
        }
    }

    float sm[2][4], sq[2][4];
    #pragma unroll
    for (int mt = 0; mt < 2; ++mt)
        #pragma unroll
        for (int r = 0; r < 4; ++r) { sm[mt][r] = 0.f; sq[mt][r] = 0.f; }
    #pragma unroll
    for (int mt = 0; mt < 2; ++mt)
        #pragma unroll
        for (int nt = 0; nt < 2; ++nt)
            #pragma unroll
            for (int r = 0; r < 4; ++r) {
                float x_ = acc[mt][nt][r];
                sm[mt][r] += x_; sq[mt][r] += x_ * x_;
            }
    #pragma unroll
    for (int mask = 1; mask <= 8; mask <<= 1)
        #pragma unroll
        for (int mt = 0; mt < 2; ++mt)
            #pragma unroll
            for (int r = 0; r < 4; ++r) {
                sm[mt][r] += __shfl_xor(sm[mt][r], mask);
                sq[mt][r] += __shfl_xor(sq[mt][r], mask);
            }
    if (c == 0) {
        #pragma unroll
        for (int mt = 0; mt < 2; ++mt)
            #pragma unroll
            for (int r = 0; r < 4; ++r) {
                red[0][mt * 16 + 4 * qd + r][w] = sm[mt][r];
                red[1][mt * 16 + 4 * qd + r][w] = sq[mt][r];
            }
    }
    __syncthreads();

    if (t < 32) {
        float s_ = 0.f, q_ = 0.f;
        #pragma unroll
        for (int w_ = 0; w_ < 16; ++w_) { s_ += red[0][t][w_]; q_ += red[1][t][w_]; }
        float mu_ = s_ * (1.f / D);
        float var = q_ * (1.f / D) - mu_ * mu_;
        mu_s2[t] = mu_;
        rs_s2[t] = rsqrtf(var + 1e-5f);
    }
    __syncthreads();

    #pragma unroll
    for (int nt = 0; nt < 2; ++nt) {
        int n = n0 + 16 * nt + c;
        float g = gamma[n], be = beta[n];
        #pragma unroll
        for (int mt = 0; mt < 2; ++mt)
            #pragma unroll
            for (int r = 0; r < 4; ++r) {
                int m = mt * 16 + 4 * qd + r;
                size_t gi = (size_t)(r0 + m) * D + n;
                out[gi] = qin[gi] + (acc[mt][nt][r] - mu_s2[m]) * rs_s2[m] * g + be;
            }
    }
}

// ---------------------------------------------------------------------------
extern "C" void kernel_launch(void* const* d_in, const int* in_sizes, int n_in,
                              void* d_out, int out_size, void* d_ws, size_t ws_size,
                              hipStream_t stream) {
    const float* q     = (const float*)d_in[0];
    const float* k     = (const float*)d_in[1];
    const float* v     = (const float*)d_in[2];
    const float* Wq    = (const float*)d_in[3];
    const float* bq    = (const float*)d_in[4];
    const float* Wk    = (const float*)d_in[5];
    const float* bk    = (const float*)d_in[6];
    const float* Wv    = (const float*)d_in[7];
    const float* bv    = (const float*)d_in[8];
    const float* Wo    = (const float*)d_in[9];
    const float* bo    = (const float*)d_in[10];
    const float* gamma = (const float*)d_in[11];
    const float* beta  = (const float*)d_in[12];
    float* out = (float*)d_out;

    const size_t NE = (size_t)B * S * D;
    unsigned short* wsu = (unsigned short*)d_ws;
    unsigned short* Qh    = wsu;
    unsigned short* Kh    = wsu + NE;
    unsigned short* VtG   = wsu + 2 * NE;
    unsigned short* WoB   = wsu + 3 * NE;
    unsigned short* accPb = WoB + (size_t)D * D;
    float* lP = (float*)(accPb + 2 * NE);

    hipLaunchKernelGGL(qkv_mfma_kernel, dim3(1536 + 256), dim3(256), 0, stream,
                       q, k, v, Wq, bq, Wk, bk, Wv, bv, Wo, WoB, Qh, Kh, VtG);
    hipLaunchKernelGGL(attn_kernel, dim3(1024), dim3(256), 0, stream,
                       Qh, Kh, VtG, accPb, lP);
    hipLaunchKernelGGL(oproj_ln_kernel, dim3(B * S / 32), dim3(1024), 0, stream,
                       accPb, lP, WoB, bo, gamma, beta, q, out);
}

// Round 3
// 179.809 us; speedup vs baseline: 1.0797x; 1.0716x over previous
//
#include <hip/hip_runtime.h>
#include <hip/hip_bf16.h>
#include <math.h>
#include <stdint.h>

#define B 4
#define S 2048
#define D 512
#define H 8
#define HD 64

typedef __attribute__((ext_vector_type(4))) int   int4v;
typedef __attribute__((ext_vector_type(8))) short short8;
typedef __attribute__((ext_vector_type(4))) short short4v;
typedef __attribute__((ext_vector_type(4))) float f32x4;

__device__ __forceinline__ unsigned short bfr(float x) {
    __bf16 h = (__bf16)x;
    union { __bf16 b; unsigned short s; } u; u.b = h; return u.s;
}
__device__ __forceinline__ float b2f(unsigned short s) {
    union { unsigned u; float f; } v; v.u = (unsigned)s << 16; return v.f;
}
__device__ __forceinline__ float ex2(float x) {
#if __has_builtin(__builtin_amdgcn_exp2f)
    return __builtin_amdgcn_exp2f(x);
#else
    return exp2f(x);
#endif
}
__device__ __forceinline__ short8 cvt8(const float* p) {
    float4 f0 = *(const float4*)p;
    float4 f1 = *(const float4*)(p + 4);
    short8 s8;
    s8[0] = (short)bfr(f0.x); s8[1] = (short)bfr(f0.y);
    s8[2] = (short)bfr(f0.z); s8[3] = (short)bfr(f0.w);
    s8[4] = (short)bfr(f1.x); s8[5] = (short)bfr(f1.y);
    s8[6] = (short)bfr(f1.z); s8[7] = (short)bfr(f1.w);
    return s8;
}

// log2e / sqrt(512): folded into Qh at projection time
#define QSCALE 0.06377229601488305f
// fixed log2-domain softmax max (scores |z| <~ 1; exact for any M). With
// k-split this makes partial (acc, l) sums EXACTLY mergeable by addition.
#define MFIX 4.0f

typedef const __attribute__((address_space(1))) unsigned char g8_t;
typedef __attribute__((address_space(3))) unsigned char l8_t;
__device__ __forceinline__ void gl_lds16(const unsigned short* g, unsigned short* l) {
#if __has_builtin(__builtin_amdgcn_global_load_lds)
    __builtin_amdgcn_global_load_lds((g8_t*)g, (l8_t*)l, 16, 0, 0);
#else
    int lane = threadIdx.x & 63;
    ((int4v*)l)[lane] = *(const int4v*)g;
#endif
}

// ===========================================================================
// Kernel 1: QKV projection (+ distributed Wo fp32->bf16 conversion).
// ===========================================================================
__global__ __launch_bounds__(256) void qkv_mfma_kernel(
    const float* __restrict__ q, const float* __restrict__ k,
    const float* __restrict__ v,
    const float* __restrict__ Wq, const float* __restrict__ bq,
    const float* __restrict__ Wk, const float* __restrict__ bk,
    const float* __restrict__ Wv, const float* __restrict__ bv,
    const float* __restrict__ Wo, unsigned short* __restrict__ WoB,
    unsigned short* __restrict__ Qh, unsigned short* __restrict__ Kh,
    unsigned short* __restrict__ VtG)
{
    const int t = threadIdx.x;
    const int bid = blockIdx.x;
    if (bid >= 1536) {
        int i = (bid - 1536) * 1024 + t * 4;
        float4 f = *(const float4*)(Wo + i);
        short4v s;
        s[0] = (short)bfr(f.x); s[1] = (short)bfr(f.y);
        s[2] = (short)bfr(f.z); s[3] = (short)bfr(f.w);
        *(short4v*)(WoB + i) = s;
        return;
    }

    __shared__ __align__(16) unsigned short Wl[64 * 72];
    __shared__ __align__(16) unsigned short Tb[4][1536];   // per-wave transpose tile

    const int x   = bid / 512;
    const int r_  = bid - x * 512;
    const int bh  = r_ >> 4;
    const int stg = r_ & 15;
    const int b = bh >> 3, h = bh & 7;
    const int L = t & 63, w = t >> 6;
    const int c = L & 15, qd = L >> 4;

    const float* Wf     = (x == 0) ? Wq : (x == 1) ? Wk : Wv;
    const float* bias_p = (x == 0) ? bq : (x == 1) ? bk : bv;
    const float* X      = (x == 0) ? q  : (x == 1) ? k  : v;

    unsigned short* Tw = Tb[w];

    {
        int row = t >> 2, col = (t & 3) * 16;
        *(short8*)&Wl[row * 72 + col]     = cvt8(Wf + t * 16);
        *(short8*)&Wl[row * 72 + col + 8] = cvt8(Wf + t * 16 + 8);
    }
    __syncthreads();

    short8 wf[4][2];
    #pragma unroll
    for (int nt = 0; nt < 4; ++nt)
        #pragma unroll
        for (int kc = 0; kc < 2; ++kc)
            wf[nt][kc] = *(const short8*)&Wl[(16 * nt + c) * 72 + kc * 32 + 8 * qd];

    if (x < 2) {
        float bias[4];
        #pragma unroll
        for (int nt = 0; nt < 4; ++nt) bias[nt] = bias_p[16 * nt + c];
        const float sc = (x == 0) ? QSCALE : 1.0f;
        #pragma unroll
        for (int ti = 0; ti < 2; ++ti) {
            const int st = stg * 8 + w * 2 + ti;
            const float* xrow = X + ((size_t)(b * S + st * 16 + c)) * D + h * HD;
            short8 af0 = cvt8(xrow + 8 * qd);
            short8 af1 = cvt8(xrow + 32 + 8 * qd);
            f32x4 acc[4];
            #pragma unroll
            for (int nt = 0; nt < 4; ++nt) {
                acc[nt] = (f32x4){bias[nt], bias[nt], bias[nt], bias[nt]};
                acc[nt] = __builtin_amdgcn_mfma_f32_16x16x32_bf16(af0, wf[nt][0], acc[nt], 0, 0, 0);
                acc[nt] = __builtin_amdgcn_mfma_f32_16x16x32_bf16(af1, wf[nt][1], acc[nt], 0, 0, 0);
            }
            #pragma unroll
            for (int nt = 0; nt < 4; ++nt)
                #pragma unroll
                for (int r = 0; r < 4; ++r)
                    Tw[(4 * qd + r) * 72 + 16 * nt + c] = bfr(acc[nt][r] * sc);
            int rw = L >> 2, cg_ = (L & 3) * 16;
            short8 s0 = *(const short8*)&Tw[rw * 72 + cg_];
            short8 s1 = *(const short8*)&Tw[rw * 72 + cg_ + 8];
            unsigned short* O = ((x == 0) ? Qh : Kh)
                              + ((size_t)(b * H + h) * S + st * 16) * HD;
            *(short8*)&O[rw * HD + cg_]     = s0;
            *(short8*)&O[rw * HD + cg_ + 8] = s1;
        }
    } else {
        f32x4 bias4[4];
        #pragma unroll
        for (int nt = 0; nt < 4; ++nt) {
            float4 bb4 = *(const float4*)(bias_p + 16 * nt + 4 * qd);
            bias4[nt] = (f32x4){bb4.x, bb4.y, bb4.z, bb4.w};
        }
        #pragma unroll
        for (int ti = 0; ti < 2; ++ti) {
            const int st = stg * 8 + w * 2 + ti;
            const float* xrow = X + ((size_t)(b * S + st * 16 + c)) * D + h * HD;
            short8 af0 = cvt8(xrow + 8 * qd);
            short8 af1 = cvt8(xrow + 32 + 8 * qd);
            f32x4 acc[4];
            #pragma unroll
            for (int nt = 0; nt < 4; ++nt) {
                acc[nt] = bias4[nt];
                acc[nt] = __builtin_amdgcn_mfma_f32_16x16x32_bf16(wf[nt][0], af0, acc[nt], 0, 0, 0);
                acc[nt] = __builtin_amdgcn_mfma_f32_16x16x32_bf16(wf[nt][1], af1, acc[nt], 0, 0, 0);
            }
            #pragma unroll
            for (int nt = 0; nt < 4; ++nt)
                #pragma unroll
                for (int r = 0; r < 4; ++r)
                    Tw[(16 * nt + 4 * qd + r) * 24 + c] = bfr(acc[nt][r]);
            short8 s0 = *(const short8*)&Tw[L * 24];
            short8 s1 = *(const short8*)&Tw[L * 24 + 8];
            unsigned short* O = VtG + (size_t)(b * H + h) * HD * S;
            *(short8*)&O[(size_t)L * S + st * 16]     = s0;
            *(short8*)&O[(size_t)L * S + st * 16 + 8] = s1;
        }
    }
}

// ===========================================================================
// Kernel 2: flash attention, 1024 blocks x 256 thr, 4 blocks/CU, 32 KB LDS.
// PV runs at K=32 via an in-LDS key permutation: within each 32-key block,
// key' = 8*qd + j  <->  QKkey = (j>>2)*16 + 4*qd + (j&3). Softmax sums are
// permutation-invariant as long as V rows use the same permutation (baked
// into the Vs staging addresses). The two QK^T short4 fragments of an
// mt-pair concatenate into a legal 16x16x32 A-fragment with ZERO data
// movement. PV MFMA count: 32 (K=16) -> 16 (K=32).
// l-sums computed by MFMA against a ones-fragment (saves 32 VALU adds/iter;
// also makes numerator/denominator use the same bf16-rounded P).
// ===========================================================================
__global__ __launch_bounds__(256, 4) void attn_kernel(
    const unsigned short* __restrict__ Qh, const unsigned short* __restrict__ Kh,
    const unsigned short* __restrict__ VtG, unsigned short* __restrict__ accPb,
    float* __restrict__ lP)
{
    __shared__ __align__(16) unsigned short Ks[2][4096];
    __shared__ __align__(16) unsigned short Vs[2][4096];

    const int idx = blockIdx.x;
    const int bh = idx & 31;
    const int rem = idx >> 5;
    const int qt = rem >> 1;
    const int ks = rem & 1;
    const int b = bh >> 3, h = bh & 7;
    const int t = threadIdx.x;
    const int w = t >> 6, L = t & 63;
    const int c = L & 15, qd = L >> 4;

    const unsigned short* Kb = Kh + ((size_t)bh * S + ks * 1024) * HD;
    const unsigned short* Vb = VtG + (size_t)bh * HD * S + ks * 1024;

    short8 qf[2][2];
    #pragma unroll
    for (int qg = 0; qg < 2; ++qg)
        #pragma unroll
        for (int kc = 0; kc < 2; ++kc)
            qf[qg][kc] = *(const short8*)(Qh
                + ((size_t)bh * S + qt * 128 + w * 32 + qg * 16 + c) * HD
                + kc * 32 + 8 * qd);

    f32x4 acc[2][4];
    f32x4 lacc[2];
    #pragma unroll
    for (int qg = 0; qg < 2; ++qg) {
        lacc[qg] = (f32x4){0.f, 0.f, 0.f, 0.f};
        #pragma unroll
        for (int dt = 0; dt < 4; ++dt) acc[qg][dt] = (f32x4){0.f, 0.f, 0.f, 0.f};
    }

    const short8 ones8 = {0x3F80, 0x3F80, 0x3F80, 0x3F80,
                          0x3F80, 0x3F80, 0x3F80, 0x3F80};   // bf16 1.0 x8

    // V staging: thread (sd = t>>3, sj = t&7) holds V^T[d = sd+32i][keys 8sj..8sj+7]
    // dest short offset: slot*512 + qd*128 + (d&15)*8 + half*4 + jj with
    //   p = sj>>2, s3 = sj&3, half = s3>>1, qd = (s3&1)*2 + (m>>2), jj = m&3
    const int sd = t >> 3, sj = t & 7;
    const int s3 = sj & 3;
    const int vslotp = sj >> 2;
    const int vadd = (s3 & 1) * 256 + (s3 >> 1) * 4;

    int4v vpre[2];
    #pragma unroll
    for (int i = 0; i < 2; ++i) {
        int bi = w + 4 * i;
        gl_lds16(Kb + (size_t)(16 * (bi >> 1) + c) * HD + (bi & 1) * 32 + qd * 8,
                 &Ks[0][bi * 512]);
        vpre[i] = *(const int4v*)(Vb + (size_t)(sd + 32 * i) * S + 8 * sj);
    }

    for (int it = 0; it < 16; ++it) {
        const int cur = it & 1, nxt = cur ^ 1;
        #pragma unroll
        for (int i = 0; i < 2; ++i) {
            int d = sd + 32 * i;
            int os = ((d >> 4) * 2 + vslotp) * 512 + (d & 15) * 8 + vadd;
            union { int4v v; short4v h[2]; } u; u.v = vpre[i];
            *(short4v*)&Vs[cur][os]       = u.h[0];
            *(short4v*)&Vs[cur][os + 128] = u.h[1];
        }
        __syncthreads();
        if (it + 1 < 16) {
            int n1 = (it + 1) * 64;
            #pragma unroll
            for (int i = 0; i < 2; ++i) {
                int bi = w + 4 * i;
                gl_lds16(Kb + (size_t)(n1 + 16 * (bi >> 1) + c) * HD + (bi & 1) * 32 + qd * 8,
                         &Ks[nxt][bi * 512]);
                vpre[i] = *(const int4v*)(Vb + (size_t)(sd + 32 * i) * S + n1 + 8 * sj);
            }
        }

        const unsigned short* KsC = Ks[cur];
        const unsigned short* VsC = Vs[cur];

        // QK^T + exp2 -> packed K=32 A-fragments ps[qg][p]
        short8 ps[2][2];
        #pragma unroll
        for (int mt = 0; mt < 4; ++mt) {
            short8 a0 = *(const short8*)(KsC + (mt * 2 + 0) * 512 + L * 8);
            short8 a1 = *(const short8*)(KsC + (mt * 2 + 1) * 512 + L * 8);
            #pragma unroll
            for (int qg = 0; qg < 2; ++qg) {
                f32x4 stv = (f32x4){-MFIX, -MFIX, -MFIX, -MFIX};
                __builtin_amdgcn_s_setprio(1);
                stv = __builtin_amdgcn_mfma_f32_16x16x32_bf16(a0, qf[qg][0], stv, 0, 0, 0);
                stv = __builtin_amdgcn_mfma_f32_16x16x32_bf16(a1, qf[qg][1], stv, 0, 0, 0);
                __builtin_amdgcn_s_setprio(0);
                float p0 = ex2(stv[0]), p1 = ex2(stv[1]);
                float p2 = ex2(stv[2]), p3 = ex2(stv[3]);
                const int pp = mt >> 1, hl = (mt & 1) * 4;
                ps[qg][pp][hl + 0] = (short)bfr(p0);
                ps[qg][pp][hl + 1] = (short)bfr(p1);
                ps[qg][pp][hl + 2] = (short)bfr(p2);
                ps[qg][pp][hl + 3] = (short)bfr(p3);
            }
        }

        __builtin_amdgcn_s_setprio(1);
        // l-sums: row-sum of P via ones-fragment
        #pragma unroll
        for (int pp = 0; pp < 2; ++pp) {
            lacc[0] = __builtin_amdgcn_mfma_f32_16x16x32_bf16(ps[0][pp], ones8, lacc[0], 0, 0, 0);
            lacc[1] = __builtin_amdgcn_mfma_f32_16x16x32_bf16(ps[1][pp], ones8, lacc[1], 0, 0, 0);
        }
        // PV at K=32 (permuted V rows match ps key ordering)
        #pragma unroll
        for (int dt = 0; dt < 4; ++dt)
            #pragma unroll
            for (int pp = 0; pp < 2; ++pp) {
                short8 vb = *(const short8*)(VsC + (dt * 2 + pp) * 512 + L * 8);
                acc[0][dt] = __builtin_amdgcn_mfma_f32_16x16x32_bf16(ps[0][pp], vb, acc[0][dt], 0, 0, 0);
                acc[1][dt] = __builtin_amdgcn_mfma_f32_16x16x32_bf16(ps[1][pp], vb, acc[1][dt], 0, 0, 0);
            }
        __builtin_amdgcn_s_setprio(0);
    }

    const int q0 = qt * 128 + w * 32;
    unsigned short* accPp = accPb + (size_t)ks * ((size_t)B * S * D)
                          + ((size_t)b * S + q0) * D + h * HD;
    #pragma unroll
    for (int qg = 0; qg < 2; ++qg) {
        if (c == 0) {
            #pragma unroll
            for (int r = 0; r < 4; ++r)
                lP[(size_t)ks * ((size_t)B * H * S) + (size_t)bh * S
                   + q0 + qg * 16 + 4 * qd + r] = lacc[qg][r];
        }
        #pragma unroll
        for (int dt = 0; dt < 4; ++dt)
            #pragma unroll
            for (int r = 0; r < 4; ++r)
                accPp[(size_t)(qg * 16 + 4 * qd + r) * D + 16 * dt + c]
                    = bfr(acc[qg][dt][r]);
    }
}

// ===========================================================================
// Kernel 3: merge k-split partials + output projection + LayerNorm + residual
// ===========================================================================
__global__ __launch_bounds__(1024) void oproj_ln_kernel(
    const unsigned short* __restrict__ accPb, const float* __restrict__ lP,
    const unsigned short* __restrict__ WoB,
    const float* __restrict__ bo, const float* __restrict__ gamma,
    const float* __restrict__ beta, const float* __restrict__ qin,
    float* __restrict__ out)
{
    __shared__ __align__(16) unsigned short As[32 * 520];
    __shared__ float red[2][32][17];
    __shared__ float linv_s[32][8];
    __shared__ float mu_s2[32], rs_s2[32];

    const int t = threadIdx.x;
    const int r0 = blockIdx.x * 32;
    const int w = t >> 6, L = t & 63;
    const int c = L & 15, qd = L >> 4;
    const int n0 = w * 32;
    const size_t NEh = (size_t)B * S * D;
    const size_t BHS = (size_t)B * H * S;

    if (t < 256) {
        int row = t >> 3, hh = t & 7;
        int bb = r0 >> 11;
        int ss = (r0 & (S - 1)) + row;
        float l0 = lP[(size_t)(bb * H + hh) * S + ss];
        float l1 = lP[BHS + (size_t)(bb * H + hh) * S + ss];
        linv_s[row][hh] = 1.f / (l0 + l1);
    }
    __syncthreads();

    #pragma unroll
    for (int i = 0; i < 4; ++i) {
        int flat = t + 1024 * i;
        int row = flat >> 7, cg4 = flat & 127;
        int col = cg4 * 4;
        size_t gi = (size_t)(r0 + row) * D + col;
        short4v a0 = *(const short4v*)(accPb + gi);
        short4v a1 = *(const short4v*)(accPb + NEh + gi);
        float li = linv_s[row][col >> 6];
        short4v s;
        #pragma unroll
        for (int j = 0; j < 4; ++j)
            s[j] = (short)bfr((b2f((unsigned short)a0[j])
                             + b2f((unsigned short)a1[j])) * li);
        *(short4v*)&As[row * 520 + col] = s;
    }
    __syncthreads();

    f32x4 acc[2][2];
    #pragma unroll
    for (int nt = 0; nt < 2; ++nt) {
        float bv_ = bo[n0 + 16 * nt + c];
        acc[0][nt] = (f32x4){bv_, bv_, bv_, bv_};
        acc[1][nt] = (f32x4){bv_, bv_, bv_, bv_};
    }

    for (int kc = 0; kc < 16; ++kc) {
        short8 a0 = *(const short8*)&As[c * 520 + kc * 32 + 8 * qd];
        short8 a1 = *(const short8*)&As[(16 + c) * 520 + kc * 32 + 8 * qd];
        #pragma unroll
        for (int nt = 0; nt < 2; ++nt) {
            short8 bf = *(const short8*)(WoB + (size_t)(n0 + 16 * nt + c) * D
                                         + kc * 32 + 8 * qd);
            acc[0][nt] = __builtin_amdgcn_mfma_f32_16x16x32_bf16(a0, bf, acc[0][nt], 0, 0, 0);
            acc[1][nt] = __builtin_amdgcn_mfma_f32_16x16x32_bf16(a1, bf, acc[1][nt], 0, 0, 0);
        }
    }

    float sm[2][4], sq[2][4];
    #pragma unroll
    for (int mt = 0; mt < 2; ++mt)
        #pragma unroll
        for (int r = 0; r < 4; ++r) { sm[mt][r] = 0.f; sq[mt][r] = 0.f; }
    #pragma unroll
    for (int mt = 0; mt < 2; ++mt)
        #pragma unroll
        for (int nt = 0; nt < 2; ++nt)
            #pragma unroll
            for (int r = 0; r < 4; ++r) {
                float x_ = acc[mt][nt][r];
                sm[mt][r] += x_; sq[mt][r] += x_ * x_;
            }
    #pragma unroll
    for (int mask = 1; mask <= 8; mask <<= 1)
        #pragma unroll
        for (int mt = 0; mt < 2; ++mt)
            #pragma unroll
            for (int r = 0; r < 4; ++r) {
                sm[mt][r] += __shfl_xor(sm[mt][r], mask);
                sq[mt][r] += __shfl_xor(sq[mt][r], mask);
            }
    if (c == 0) {
        #pragma unroll
        for (int mt = 0; mt < 2; ++mt)
            #pragma unroll
            for (int r = 0; r < 4; ++r) {
                red[0][mt * 16 + 4 * qd + r][w] = sm[mt][r];
                red[1][mt * 16 + 4 * qd + r][w] = sq[mt][r];
            }
    }
    __syncthreads();

    if (t < 32) {
        float s_ = 0.f, q_ = 0.f;
        #pragma unroll
        for (int w_ = 0; w_ < 16; ++w_) { s_ += red[0][t][w_]; q_ += red[1][t][w_]; }
        float mu_ = s_ * (1.f / D);
        float var = q_ * (1.f / D) - mu_ * mu_;
        mu_s2[t] = mu_;
        rs_s2[t] = rsqrtf(var + 1e-5f);
    }
    __syncthreads();

    #pragma unroll
    for (int nt = 0; nt < 2; ++nt) {
        int n = n0 + 16 * nt + c;
        float g = gamma[n], be = beta[n];
        #pragma unroll
        for (int mt = 0; mt < 2; ++mt)
            #pragma unroll
            for (int r = 0; r < 4; ++r) {
                int m = mt * 16 + 4 * qd + r;
                size_t gi = (size_t)(r0 + m) * D + n;
                out[gi] = qin[gi] + (acc[mt][nt][r] - mu_s2[m]) * rs_s2[m] * g + be;
            }
    }
}

// ---------------------------------------------------------------------------
extern "C" void kernel_launch(void* const* d_in, const int* in_sizes, int n_in,
                              void* d_out, int out_size, void* d_ws, size_t ws_size,
                              hipStream_t stream) {
    const float* q     = (const float*)d_in[0];
    const float* k     = (const float*)d_in[1];
    const float* v     = (const float*)d_in[2];
    const float* Wq    = (const float*)d_in[3];
    const float* bq    = (const float*)d_in[4];
    const float* Wk    = (const float*)d_in[5];
    const float* bk    = (const float*)d_in[6];
    const float* Wv    = (const float*)d_in[7];
    const float* bv    = (const float*)d_in[8];
    const float* Wo    = (const float*)d_in[9];
    const float* bo    = (const float*)d_in[10];
    const float* gamma = (const float*)d_in[11];
    const float* beta  = (const float*)d_in[12];
    float* out = (float*)d_out;

    const size_t NE = (size_t)B * S * D;
    unsigned short* wsu = (unsigned short*)d_ws;
    unsigned short* Qh    = wsu;
    unsigned short* Kh    = wsu + NE;
    unsigned short* VtG   = wsu + 2 * NE;
    unsigned short* WoB   = wsu + 3 * NE;
    unsigned short* accPb = WoB + (size_t)D * D;
    float* lP = (float*)(accPb + 2 * NE);

    hipLaunchKernelGGL(qkv_mfma_kernel, dim3(1536 + 256), dim3(256), 0, stream,
                       q, k, v, Wq, bq, Wk, bk, Wv, bv, Wo, WoB, Qh, Kh, VtG);
    hipLaunchKernelGGL(attn_kernel, dim3(1024), dim3(256), 0, stream,
                       Qh, Kh, VtG, accPb, lP);
    hipLaunchKernelGGL(oproj_ln_kernel, dim3(B * S / 32), dim3(1024), 0, stream,
                       accPb, lP, WoB, bo, gamma, beta, q, out);
}